// Round 15
// baseline (738.308 us; speedup 1.0000x reference)
//
#include <hip/hip_runtime.h>
#include <hip/hip_cooperative_groups.h>
#include <hip/hip_bf16.h>
#include <math.h>

#define DD 128
#define EPS 1e-5f
#define GCH 512      // histogram/scatter chunks == cooperative grid
#define BUKN 256     // nodes per bucket
#define MAXBUK 400   // >= ceil(N/BUKN); N=100000 -> 391
#define STG 5120     // csr_finalize LDS staging capacity (uints)
#define YSP (DD + 8) // gemm epilogue staging row stride

using bf16x8 = __attribute__((ext_vector_type(8))) __bf16;
using f32x4  = __attribute__((ext_vector_type(4))) float;
using u32x4  = __attribute__((ext_vector_type(4))) uint;
union U16B { u32x4 u; bf16x8 b; ushort s[8]; };

__device__ inline ushort f2b(float f) {
    uint u = __float_as_uint(f);
    return (ushort)((u + 0x7fffu + ((u >> 16) & 1u)) >> 16);
}
__device__ inline float b2f(ushort h) { return __uint_as_float(((uint)h) << 16); }
__device__ inline float blo(uint m) { return __uint_as_float(m << 16); }
__device__ inline float bhi(uint m) { return __uint_as_float(m & 0xffff0000u); }

// ---------------- cooperative preprocessing: prep + CSR counting sort in ONE launch ----------------
__global__ __launch_bounds__(256) void csr_build_coop(
    const int* __restrict__ ei, int* __restrict__ gh, int* __restrict__ total,
    int* __restrict__ bukbase, int* __restrict__ offs, float* __restrict__ dis,
    uint* __restrict__ pairs, int* __restrict__ ebuf,
    const float* __restrict__ skip_w, const float* __restrict__ readout_w,
    const float* __restrict__ emb_w, const float* __restrict__ gcn_w,
    float* __restrict__ u, ushort* __restrict__ WTall, float* __restrict__ stats,
    int ne, int nbuk, int n)
{
    cooperative_groups::grid_group grid = cooperative_groups::this_grid();
    int b = blockIdx.x;   // 0..GCH-1
    int t = threadIdx.x;
    __shared__ uint stage[STG];            // aliased per phase (20 KB)
    __shared__ int cnt[BUKN], cur2[BUKN];
    __shared__ int wsum[4];

    int chunk = (ne + GCH - 1) / GCH;
    int e0 = b * chunk, e1 = min(ne, e0 + chunk);

    // ---- phase 0: small prep (blocks 0..8) ----
    if (b < 4) {
        if (t < DD) {
            float s = 0.f;
            const float* sw = skip_w + b * DD * DD + t * DD;
            const float* rw = readout_w + b * DD;
            for (int j = 0; j < DD; j++) s += sw[j] * rw[j];
            u[b * DD + t] = s;
        }
    } else if (b < 8) {
        int w = b - 4;  // 0 = emb, 1..3 = gcn layer w-1
        const float* W = (w == 0) ? emb_w : gcn_w + (size_t)(w - 1) * DD * DD;
        ushort* WT = WTall + (size_t)w * DD * DD;
        for (int i = t; i < DD * DD; i += 256) {
            int k = i >> 7, nn = i & 127;
            WT[nn * DD + k] = f2b(W[i]);
        }
    } else if (b == 8) {
        for (int i = t; i < 3 * 2 * DD; i += 256) stats[i] = 0.f;
    }

    // ---- phase 1: per-chunk histogram ----
    {
        int* hist = (int*)stage;
        for (int i = t; i < nbuk; i += 256) hist[i] = 0;
        __syncthreads();
        for (int e = e0 + t; e < e1; e += 256)
            atomicAdd(&hist[ei[ne + e] / BUKN], 1);
        __syncthreads();
        for (int i = t; i < nbuk; i += 256)
            gh[(size_t)b * nbuk + i] = hist[i];
    }
    grid.sync();

    // ---- phase 2: per-bucket column scan over chunks ----
    {
        int k = b * 4 + (t >> 6);
        int lane = t & 63;
        if (k < nbuk) {
            const int PER = GCH / 64;  // 8
            int v[PER]; int s = 0;
            #pragma unroll
            for (int j = 0; j < PER; j++) { v[j] = gh[(size_t)(PER * lane + j) * nbuk + k]; s += v[j]; }
            int ps = s;
            #pragma unroll
            for (int off = 1; off < 64; off <<= 1) { int x = __shfl_up(ps, off); if (lane >= off) ps += x; }
            int run = ps - s;
            #pragma unroll
            for (int j = 0; j < PER; j++) { gh[(size_t)(PER * lane + j) * nbuk + k] = run; run += v[j]; }
            if (lane == 63) total[k] = run;
        }
    }
    grid.sync();

    // ---- phase 3: bucket-base scan (block 0, 512 slots) ----
    if (b == 0) {
        int* sb = (int*)stage;
        sb[t] = (t < nbuk) ? total[t] : 0;
        sb[t + 256] = (t + 256 < nbuk) ? total[t + 256] : 0;
        __syncthreads();
        for (int off = 1; off < 512; off <<= 1) {
            int a0 = sb[t], a1 = sb[t + 256];
            int b0 = (t >= off) ? sb[t - off] : 0;
            int b1 = (t + 256 >= off) ? sb[t + 256 - off] : 0;
            __syncthreads();
            sb[t] = a0 + b0; sb[t + 256] = a1 + b1;
            __syncthreads();
        }
        if (t < nbuk) bukbase[t] = (t == 0) ? 0 : sb[t - 1];
        if (t + 256 < nbuk) bukbase[t + 256] = sb[t + 255];
        if (t == 0) { bukbase[nbuk] = sb[nbuk - 1]; offs[n] = ne; }
    }
    grid.sync();

    // ---- phase 4: scatter into bucket-grouped pairs (LDS cursors only) ----
    {
        int* cur = (int*)stage;
        for (int i = t; i < nbuk; i += 256)
            cur[i] = bukbase[i] + gh[(size_t)b * nbuk + i];
        __syncthreads();
        for (int e = e0 + t; e < e1; e += 256) {
            int r = ei[e];
            int c = ei[ne + e];
            int pos = atomicAdd(&cur[c / BUKN], 1);
            pairs[pos] = ((uint)r << 8) | (uint)(c & (BUKN - 1));
        }
    }
    grid.sync();

    // ---- phase 5: finalize buckets (grid-stride) ----
    for (int bb = b; bb < nbuk; bb += GCH) {
        cnt[t] = 0;
        __syncthreads();
        int node0 = bb * BUKN;
        int wbeg = bukbase[bb], wend = bukbase[bb + 1];
        int wlen = wend - wbeg;
        bool fits = (wlen <= STG);
        if (fits) {
            for (int i = t; i < wlen; i += 256) {
                uint p = pairs[wbeg + i];
                stage[i] = p;
                atomicAdd(&cnt[p & (BUKN - 1u)], 1);
            }
        } else {
            for (int e = wbeg + t; e < wend; e += 256)
                atomicAdd(&cnt[pairs[e] & (BUKN - 1u)], 1);
        }
        __syncthreads();
        {
            int c = cnt[t];
            int ps = c;
            int lane = t & 63, wv = t >> 6;
            #pragma unroll
            for (int off = 1; off < 64; off <<= 1) { int x = __shfl_up(ps, off); if (lane >= off) ps += x; }
            if (lane == 63) wsum[wv] = ps;
            __syncthreads();
            int wb = 0;
            #pragma unroll
            for (int wv2 = 0; wv2 < 4; wv2++) if (wv2 < wv) wb += wsum[wv2];
            int lo = wbeg + wb + ps - c;
            int node = node0 + t;
            if (node < n) { offs[node] = lo; dis[node] = rsqrtf((float)(c + 1)); }
            cur2[t] = lo;
        }
        __syncthreads();
        if (fits) {
            for (int i = t; i < wlen; i += 256) {
                uint p = stage[i];
                int pos = atomicAdd(&cur2[p & (BUKN - 1u)], 1);
                ebuf[pos] = (int)(p >> 8);
            }
        } else {
            for (int e = wbeg + t; e < wend; e += 256) {
                uint p = pairs[e];
                int pos = atomicAdd(&cur2[p & (BUKN - 1u)], 1);
                ebuf[pos] = (int)(p >> 8);
            }
        }
        __syncthreads();
    }
}

// ---------------- fused MFMA GEMM ----------------
__global__ __launch_bounds__(256) void gemm_fused(
    const void* __restrict__ Xv, int xf32,
    const ushort* __restrict__ WT,
    const float* __restrict__ bias, const float* __restrict__ scale,
    const float* __restrict__ stats, const float* __restrict__ bng, const float* __restrict__ bnb, float invN,
    const float* __restrict__ uvec, float* __restrict__ logits, int dot_init_mode,
    ushort* __restrict__ Y, int nrows)
{
    __shared__ float As[DD], Bs[DD], Us[DD];
    __shared__ ushort Ys[4][32][YSP];
    int t = threadIdx.x;
    bool has_bn = (stats != nullptr);
    bool has_u  = (uvec != nullptr);
    if (has_bn && t < DD) {
        float mean = stats[t] * invN;
        float var = stats[DD + t] * invN - mean * mean;
        float a = bng[t] * rsqrtf(var + EPS);
        As[t] = a; Bs[t] = bnb[t] - mean * a;
    }
    if (has_u && t < DD) Us[t] = uvec[t];
    if (has_bn || has_u) __syncthreads();

    int wv = t >> 6;
    int lane = t & 63;
    int l15 = lane & 15;
    int kg = lane >> 4;
    int row0 = blockIdx.x * 128 + wv * 32;

    f32x4 acc[2][8];
    #pragma unroll
    for (int mt = 0; mt < 2; mt++)
        #pragma unroll
        for (int nt = 0; nt < 8; nt++) acc[mt][nt] = (f32x4){0.f, 0.f, 0.f, 0.f};

    int rA0 = min(row0 + l15, nrows - 1);
    int rA1 = min(row0 + 16 + l15, nrows - 1);
    float dot0 = 0.f, dot1 = 0.f;

    #pragma unroll
    for (int ks = 0; ks < 4; ks++) {
        U16B a0, a1;
        int d0 = ks * 32 + kg * 8;
        if (xf32) {
            const float* x0 = (const float*)Xv + (size_t)rA0 * DD + d0;
            const float* x1 = (const float*)Xv + (size_t)rA1 * DD + d0;
            f32x4 p0 = *(const f32x4*)x0;
            f32x4 q0 = *(const f32x4*)(x0 + 4);
            f32x4 p1 = *(const f32x4*)x1;
            f32x4 q1 = *(const f32x4*)(x1 + 4);
            a0.s[0]=f2b(p0.x); a0.s[1]=f2b(p0.y); a0.s[2]=f2b(p0.z); a0.s[3]=f2b(p0.w);
            a0.s[4]=f2b(q0.x); a0.s[5]=f2b(q0.y); a0.s[6]=f2b(q0.z); a0.s[7]=f2b(q0.w);
            a1.s[0]=f2b(p1.x); a1.s[1]=f2b(p1.y); a1.s[2]=f2b(p1.z); a1.s[3]=f2b(p1.w);
            a1.s[4]=f2b(q1.x); a1.s[5]=f2b(q1.y); a1.s[6]=f2b(q1.z); a1.s[7]=f2b(q1.w);
        } else {
            const ushort* X = (const ushort*)Xv;
            a0.u = *(((const u32x4*)(X + (size_t)rA0 * DD)) + ks * 4 + kg);
            a1.u = *(((const u32x4*)(X + (size_t)rA1 * DD)) + ks * 4 + kg);
            if (has_bn || has_u) {
                #pragma unroll
                for (int j = 0; j < 8; j++) {
                    float v0 = b2f(a0.s[j]);
                    float v1 = b2f(a1.s[j]);
                    if (has_bn) {
                        float A = As[d0 + j], B = Bs[d0 + j];
                        v0 = fmaxf(fmaf(A, v0, B), 0.f);
                        v1 = fmaxf(fmaf(A, v1, B), 0.f);
                        a0.s[j] = f2b(v0); a1.s[j] = f2b(v1);
                    }
                    if (has_u) {
                        float uu = Us[d0 + j];
                        dot0 = fmaf(v0, uu, dot0);
                        dot1 = fmaf(v1, uu, dot1);
                    }
                }
            }
        }
        #pragma unroll
        for (int nt = 0; nt < 8; nt++) {
            U16B b;
            b.u = ((const u32x4*)(WT + (size_t)(nt * 16 + l15) * DD))[ks * 4 + kg];
            acc[0][nt] = __builtin_amdgcn_mfma_f32_16x16x32_bf16(a0.b, b.b, acc[0][nt], 0, 0, 0);
            acc[1][nt] = __builtin_amdgcn_mfma_f32_16x16x32_bf16(a1.b, b.b, acc[1][nt], 0, 0, 0);
        }
    }

    if (has_u) {
        dot0 += __shfl_xor(dot0, 16); dot0 += __shfl_xor(dot0, 32);
        dot1 += __shfl_xor(dot1, 16); dot1 += __shfl_xor(dot1, 32);
        if (kg == 0) {
            int r0 = row0 + l15, r1 = row0 + 16 + l15;
            if (r0 < nrows) logits[r0] = dot_init_mode ? dot0 : (logits[r0] + dot0);
            if (r1 < nrows) logits[r1] = dot_init_mode ? dot1 : (logits[r1] + dot1);
        }
    }

    #pragma unroll
    for (int mt = 0; mt < 2; mt++) {
        #pragma unroll
        for (int r = 0; r < 4; r++) {
            int lrow = mt * 16 + kg * 4 + r;
            int grow = row0 + lrow;
            float s = scale ? (grow < nrows ? scale[grow] : 0.f) : 1.f;
            #pragma unroll
            for (int nt = 0; nt < 8; nt++) {
                int col = nt * 16 + l15;
                float v = acc[mt][nt][r];
                if (bias) v += bias[col];
                Ys[wv][lrow][col] = f2b(v * s);
            }
        }
    }
    __syncthreads();
    {
        int rr = lane >> 1;
        int hh = lane & 1;
        int grow = row0 + rr;
        if (grow < nrows) {
            const ushort* src = &Ys[wv][rr][hh * 64];
            ushort* dst = Y + (size_t)grow * DD + hh * 64;
            #pragma unroll
            for (int q = 0; q < 8; q++)
                ((u32x4*)dst)[q] = ((const u32x4*)src)[q];
        }
    }
}

// ---------------- aggregation: one wave per node, 16B/lane, 4 edges/wave-instruction ----------------
__global__ __launch_bounds__(256) void aggregate(const ushort* __restrict__ hl2, const int* __restrict__ ebuf,
                                                 const int* __restrict__ offs, const float* __restrict__ dis,
                                                 ushort* __restrict__ aggb, int n) {
    int w = threadIdx.x >> 6;
    int lane = threadIdx.x & 63;
    int g = lane >> 4;
    int c = lane & 15;
    int v = blockIdx.x * 4 + w;
    if (v >= n) return;
    const u32x4* base = (const u32x4*)hl2;

    float acc[8];
    #pragma unroll
    for (int q = 0; q < 8; q++) acc[q] = 0.f;

    int e0 = offs[v], e1 = offs[v + 1];
    int cnt = (e1 - e0) + 1;

    #define ACCM(M) { \
        acc[0] += blo((M).x); acc[1] += bhi((M).x); \
        acc[2] += blo((M).y); acc[3] += bhi((M).y); \
        acc[4] += blo((M).z); acc[5] += bhi((M).z); \
        acc[6] += blo((M).w); acc[7] += bhi((M).w); }

    int jb = 0;
    for (; jb + 16 <= cnt; jb += 16) {
        int j0 = jb + g;
        int s0 = (j0 == 0) ? v : ebuf[e0 + j0 - 1];
        int s1 = ebuf[e0 + jb + g + 3];
        int s2 = ebuf[e0 + jb + g + 7];
        int s3 = ebuf[e0 + jb + g + 11];
        u32x4 m0 = base[(size_t)s0 * 16 + c];
        u32x4 m1 = base[(size_t)s1 * 16 + c];
        u32x4 m2 = base[(size_t)s2 * 16 + c];
        u32x4 m3 = base[(size_t)s3 * 16 + c];
        ACCM(m0); ACCM(m1); ACCM(m2); ACCM(m3);
    }
    for (; jb < cnt; jb += 4) {
        int j = jb + g;
        if (j < cnt) {
            int s = (j == 0) ? v : ebuf[e0 + j - 1];
            u32x4 m = base[(size_t)s * 16 + c];
            ACCM(m);
        }
    }
    #undef ACCM

    #pragma unroll
    for (int q = 0; q < 8; q++) {
        acc[q] += __shfl_xor(acc[q], 16);
        acc[q] += __shfl_xor(acc[q], 32);
    }
    if (g == 0) {
        float dv = dis[v];
        u32x4 o;
        o.x = ((uint)f2b(acc[1] * dv) << 16) | (uint)f2b(acc[0] * dv);
        o.y = ((uint)f2b(acc[3] * dv) << 16) | (uint)f2b(acc[2] * dv);
        o.z = ((uint)f2b(acc[5] * dv) << 16) | (uint)f2b(acc[4] * dv);
        o.w = ((uint)f2b(acc[7] * dv) << 16) | (uint)f2b(acc[6] * dv);
        ((u32x4*)aggb)[(size_t)v * 16 + c] = o;
    }
}

// ---------------- batchnorm stats (bf16 input, fp32 accum) ----------------
__global__ __launch_bounds__(1024) void bn_stats_b(const ushort* __restrict__ aggb, float* stats, int n) {
    int lane = threadIdx.x & 63;
    int rg = threadIdx.x >> 6;
    float sx = 0.f, sy = 0.f, qx = 0.f, qy = 0.f;
    for (int i = blockIdx.x * 16 + rg; i < n; i += gridDim.x * 16) {
        uint m = ((const uint*)aggb)[(size_t)i * 64 + lane];
        float vx = blo(m), vy = bhi(m);
        sx += vx; sy += vy; qx += vx * vx; qy += vy * vy;
    }
    __shared__ float4 red[16][64];
    red[rg][lane] = make_float4(sx, sy, qx, qy);
    __syncthreads();
    if (rg == 0) {
        float4 a = red[0][lane];
        #pragma unroll
        for (int r = 1; r < 16; r++) {
            float4 x2 = red[r][lane];
            a.x += x2.x; a.y += x2.y; a.z += x2.z; a.w += x2.w;
        }
        atomicAdd(&stats[2 * lane], a.x);
        atomicAdd(&stats[2 * lane + 1], a.y);
        atomicAdd(&stats[DD + 2 * lane], a.z);
        atomicAdd(&stats[DD + 2 * lane + 1], a.w);
    }
}

// ---------------- last layer: BN+relu+dot+sigmoid+output ----------------
__global__ __launch_bounds__(256) void bn_dot_fin(const ushort* __restrict__ aggb, const float* __restrict__ stats,
                                                  const float* __restrict__ g, const float* __restrict__ b,
                                                  const float* __restrict__ uvec, const float* __restrict__ logits,
                                                  float* __restrict__ out, int n, float invN) {
    __shared__ float As[DD], Bs[DD], Us[DD];
    int t = threadIdx.x;
    if (t < DD) {
        float mean = stats[t] * invN;
        float var = stats[DD + t] * invN - mean * mean;
        float a = g[t] * rsqrtf(var + EPS);
        As[t] = a; Bs[t] = b[t] - mean * a; Us[t] = uvec[t];
    }
    __syncthreads();
    int w = t >> 6, lane = t & 63;
    int v = blockIdx.x * 4 + w;
    if (v >= n) return;
    uint m = ((const uint*)aggb)[(size_t)v * 64 + lane];
    int d0 = 2 * lane;
    float f0 = fmaxf(fmaf(As[d0], blo(m), Bs[d0]), 0.f);
    float f1 = fmaxf(fmaf(As[d0 + 1], bhi(m), Bs[d0 + 1]), 0.f);
    float c = f0 * Us[d0] + f1 * Us[d0 + 1];
    #pragma unroll
    for (int off = 32; off; off >>= 1) c += __shfl_down(c, off);
    if (lane == 0) {
        float xf = logits[v] + c;
        out[v] = xf;
        out[n + v] = 1.f / (1.f + expf(-xf));
    }
}

// ---------------- host ----------------

static inline size_t align_up(size_t x, size_t a) { return (x + a - 1) & ~(a - 1); }

extern "C" void kernel_launch(void* const* d_in, const int* in_sizes, int n_in,
                              void* d_out, int out_size, void* d_ws, size_t ws_size,
                              hipStream_t stream) {
    const float* x       = (const float*)d_in[0];
    const int*   ei      = (const int*)d_in[1];
    const float* emb_w   = (const float*)d_in[2];
    const float* emb_b   = (const float*)d_in[3];
    const float* gcn_w   = (const float*)d_in[4];
    // d_in[5] = gcn_b: no-op (constant shift immediately normalized away by BatchNorm)
    const float* bn_g    = (const float*)d_in[6];
    const float* bn_b    = (const float*)d_in[7];
    const float* skip_w  = (const float*)d_in[8];
    const float* readout = (const float*)d_in[9];
    float* out = (float*)d_out;

    int N = in_sizes[0] / DD;
    int E = in_sizes[1] / 2;
    int NBUK = (N + BUKN - 1) / BUKN;   // 391 <= MAXBUK
    const float invN = 1.0f / N;

    char* p = (char*)d_ws;
    size_t off = 0;
    auto alloc = [&](size_t bytes) { void* r = p + off; off = align_up(off + bytes, 256); return r; };
    float*  dis     = (float*) alloc((size_t)N * 4);
    int*    offs    = (int*)   alloc((size_t)(N + 1) * 4);
    int*    ebuf    = (int*)   alloc((size_t)E * 4);
    uint*   pairs   = (uint*)  alloc((size_t)E * 4);
    int*    gh      = (int*)   alloc((size_t)GCH * NBUK * 4);
    int*    total   = (int*)   alloc((size_t)NBUK * 4);
    int*    bukbase = (int*)   alloc((size_t)(NBUK + 1) * 4);
    float*  u       = (float*) alloc(4 * DD * 4);
    float*  stats   = (float*) alloc(3 * 2 * DD * 4);
    ushort* WTall   = (ushort*)alloc(4 * (size_t)DD * DD * 2);
    float*  logits  = (float*) alloc((size_t)N * 4);
    ushort* hB      = (ushort*)alloc((size_t)N * DD * 2);
    ushort* hl2B    = (ushort*)alloc((size_t)N * DD * 2);
    ushort* aggB    = (ushort*)alloc((size_t)N * DD * 2);
    (void)ws_size;

    int gG = (N + 127) / 128;

    // cooperative preprocessing: prep + full CSR build in one launch
    {
        void* cargs[] = {
            (void*)&ei, (void*)&gh, (void*)&total, (void*)&bukbase, (void*)&offs, (void*)&dis,
            (void*)&pairs, (void*)&ebuf, (void*)&skip_w, (void*)&readout, (void*)&emb_w,
            (void*)&gcn_w, (void*)&u, (void*)&WTall, (void*)&stats, (void*)&E, (void*)&NBUK, (void*)&N
        };
        hipLaunchCooperativeKernel((void*)csr_build_coop, dim3(GCH), dim3(256), cargs, 0, stream);
    }

    // embedding: h = x @ emb_w + emb_b  (reads fp32 x directly)
    gemm_fused<<<gG, 256, 0, stream>>>(x, 1, WTall, emb_b, nullptr,
                                       nullptr, nullptr, nullptr, invN,
                                       nullptr, nullptr, 0, hB, N);

    for (int l = 0; l < 3; l++) {  // layer 3's output is dead (skip uses feats[0..3])
        const ushort* Xin = (l == 0) ? hB : aggB;
        const float* st   = (l == 0) ? nullptr : stats + (size_t)(l - 1) * 2 * DD;
        const float* g    = (l == 0) ? nullptr : bn_g + (size_t)(l - 1) * DD;
        const float* bb   = (l == 0) ? nullptr : bn_b + (size_t)(l - 1) * DD;
        gemm_fused<<<gG, 256, 0, stream>>>(Xin, 0, WTall + (size_t)(l + 1) * DD * DD, nullptr, dis,
                                           st, g, bb, invN,
                                           u + (size_t)l * DD, logits, (l == 0) ? 1 : 0, hl2B, N);
        aggregate<<<(N + 3) / 4, 256, 0, stream>>>(hl2B, ebuf, offs, dis, aggB, N);
        bn_stats_b<<<256, 1024, 0, stream>>>(aggB, stats + (size_t)l * 2 * DD, N);
    }
    // feats[3] = BNrelu(agg_2): out = logits + feats[3].u[3]; sigmoid
    bn_dot_fin<<<(N + 3) / 4, 256, 0, stream>>>(aggB, stats + 2 * 2 * DD, bn_g + 2 * DD, bn_b + 2 * DD,
                                                u + 3 * DD, logits, out, N, invN);
}

// Round 16
// 497.150 us; speedup vs baseline: 1.4851x; 1.4851x over previous
//
#include <hip/hip_runtime.h>
#include <hip/hip_bf16.h>
#include <math.h>

#define DD 128
#define EPS 1e-5f
#define GCH 256      // histogram/scatter chunks (must equal scatter grid)
#define BUKN 256     // nodes per bucket
#define MAXBUK 400   // >= ceil(N/BUKN); N=100000 -> 391
#define STG 5120     // csr_finalize LDS staging capacity (window avg ~4096)
#define YSP (DD + 8) // epilogue staging row stride (pad breaks bank aliasing)

using bf16x8 = __attribute__((ext_vector_type(8))) __bf16;
using f32x4  = __attribute__((ext_vector_type(4))) float;
using u32x4  = __attribute__((ext_vector_type(4))) uint;
union U16B { u32x4 u; bf16x8 b; ushort s[8]; };

__device__ inline ushort f2b(float f) {
    uint u = __float_as_uint(f);
    return (ushort)((u + 0x7fffu + ((u >> 16) & 1u)) >> 16);
}
__device__ inline float b2f(ushort h) { return __uint_as_float(((uint)h) << 16); }
__device__ inline float blo(uint m) { return __uint_as_float(m << 16); }
__device__ inline float bhi(uint m) { return __uint_as_float(m & 0xffff0000u); }

// ---------------- CSR build: contention-free counting sort (256-node buckets) ----------------

__global__ __launch_bounds__(256) void count_hist(const int* __restrict__ ei, int* __restrict__ gh,
                                                  int ne, int nbuk) {
    __shared__ int hist[MAXBUK];
    for (int i = threadIdx.x; i < nbuk; i += 256) hist[i] = 0;
    __syncthreads();
    int chunk = (ne + GCH - 1) / GCH;
    int e0 = blockIdx.x * chunk, e1 = min(ne, e0 + chunk);
    for (int e = e0 + threadIdx.x; e < e1; e += 256)
        atomicAdd(&hist[ei[ne + e] / BUKN], 1);
    __syncthreads();
    for (int i = threadIdx.x; i < nbuk; i += 256)
        gh[(size_t)blockIdx.x * nbuk + i] = hist[i];
}

// per-bucket exclusive scan over the GCH chunks; gh[g][k] -> prefix, total[k]
__global__ __launch_bounds__(256) void colscan(int* __restrict__ gh, int* __restrict__ total, int nbuk) {
    int k = blockIdx.x * 4 + (threadIdx.x >> 6);
    int lane = threadIdx.x & 63;
    if (k >= nbuk) return;
    const int PER = GCH / 64;  // 4
    int v[PER]; int s = 0;
    #pragma unroll
    for (int j = 0; j < PER; j++) { v[j] = gh[(size_t)(PER * lane + j) * nbuk + k]; s += v[j]; }
    int ps = s;
    #pragma unroll
    for (int off = 1; off < 64; off <<= 1) { int t = __shfl_up(ps, off); if (lane >= off) ps += t; }
    int run = ps - s;
    #pragma unroll
    for (int j = 0; j < PER; j++) { gh[(size_t)(PER * lane + j) * nbuk + k] = run; run += v[j]; }
    if (lane == 63) total[k] = run;
}

// exclusive scan of bucket totals -> bukbase[0..nbuk]; offs[n] = ne
__global__ __launch_bounds__(1024) void bukscan(const int* __restrict__ total, int* __restrict__ bukbase,
                                                int* __restrict__ offs, int nbuk, int n, int ne) {
    __shared__ int sm[1024];
    int t = threadIdx.x;
    sm[t] = (t < nbuk) ? total[t] : 0;
    __syncthreads();
    for (int off = 1; off < 1024; off <<= 1) {
        int a = sm[t], b = (t >= off) ? sm[t - off] : 0;
        __syncthreads();
        sm[t] = a + b;
        __syncthreads();
    }
    if (t < nbuk) bukbase[t] = (t == 0) ? 0 : sm[t - 1];
    if (t == 0) { bukbase[nbuk] = sm[nbuk - 1]; offs[n] = ne; }
}

// scatter edges into bucket-grouped pairs; LDS cursors only (no global atomics)
__global__ __launch_bounds__(256) void scatter(const int* __restrict__ ei, const int* __restrict__ gh,
                                               const int* __restrict__ bukbase, uint* __restrict__ pairs,
                                               int ne, int nbuk) {
    __shared__ int cur[MAXBUK];
    int g = blockIdx.x;
    for (int i = threadIdx.x; i < nbuk; i += 256)
        cur[i] = bukbase[i] + gh[(size_t)g * nbuk + i];
    __syncthreads();
    int chunk = (ne + GCH - 1) / GCH;
    int e0 = g * chunk, e1 = min(ne, e0 + chunk);
    for (int e = e0 + threadIdx.x; e < e1; e += 256) {
        int r = ei[e];
        int c = ei[ne + e];
        int pos = atomicAdd(&cur[c / BUKN], 1);
        pairs[pos] = ((uint)r << 8) | (uint)(c & (BUKN - 1));
    }
}

// one block per bucket (256 nodes): degrees via LDS, cross-wave scan -> offs/dis, place edges
__global__ __launch_bounds__(256) void csr_finalize(const uint* __restrict__ pairs, const int* __restrict__ bukbase,
                                                    int* __restrict__ offs, float* __restrict__ dis,
                                                    int* __restrict__ ebuf, int n) {
    __shared__ int cnt[BUKN], cur2[BUKN];
    __shared__ int wsum[4];
    __shared__ uint stage[STG];
    int b = blockIdx.x;
    int t = threadIdx.x;
    int node0 = b * BUKN;
    cnt[t] = 0;
    __syncthreads();
    int wbeg = bukbase[b], wend = bukbase[b + 1];
    int wlen = wend - wbeg;
    bool fits = (wlen <= STG);
    if (fits) {
        for (int i = t; i < wlen; i += 256) {
            uint p = pairs[wbeg + i];
            stage[i] = p;
            atomicAdd(&cnt[p & (BUKN - 1u)], 1);
        }
    } else {
        for (int e = wbeg + t; e < wend; e += 256)
            atomicAdd(&cnt[pairs[e] & (BUKN - 1u)], 1);
    }
    __syncthreads();
    {
        int c = cnt[t];
        int ps = c;
        int lane = t & 63, wv = t >> 6;
        #pragma unroll
        for (int off = 1; off < 64; off <<= 1) { int x = __shfl_up(ps, off); if (lane >= off) ps += x; }
        if (lane == 63) wsum[wv] = ps;
        __syncthreads();
        int wb = 0;
        #pragma unroll
        for (int wv2 = 0; wv2 < 4; wv2++) if (wv2 < wv) wb += wsum[wv2];
        int lo = wbeg + wb + ps - c;   // exclusive prefix
        int node = node0 + t;
        if (node < n) { offs[node] = lo; dis[node] = rsqrtf((float)(c + 1)); }
        cur2[t] = lo;
    }
    __syncthreads();
    if (fits) {
        for (int i = t; i < wlen; i += 256) {
            uint p = stage[i];
            int pos = atomicAdd(&cur2[p & (BUKN - 1u)], 1);
            ebuf[pos] = (int)(p >> 8);
        }
    } else {
        for (int e = wbeg + t; e < wend; e += 256) {
            uint p = pairs[e];
            int pos = atomicAdd(&cur2[p & (BUKN - 1u)], 1);
            ebuf[pos] = (int)(p >> 8);
        }
    }
}

// ---------------- merged small prep: u vectors, WT bf16 transpose, stats zero ----------------
__global__ __launch_bounds__(256) void prep_small(const float* __restrict__ skip_w, const float* __restrict__ readout_w,
                                                  const float* __restrict__ emb_w, const float* __restrict__ gcn_w,
                                                  float* __restrict__ u, ushort* __restrict__ WTall,
                                                  float* __restrict__ stats) {
    int b = blockIdx.x;
    int t = threadIdx.x;
    if (b < 4) {
        if (t < DD) {
            float s = 0.f;
            const float* sw = skip_w + b * DD * DD + t * DD;
            const float* rw = readout_w + b * DD;
            for (int j = 0; j < DD; j++) s += sw[j] * rw[j];
            u[b * DD + t] = s;
        }
    } else if (b < 8) {
        int w = b - 4;  // 0 = emb, 1..3 = gcn layer w-1
        const float* W = (w == 0) ? emb_w : gcn_w + (size_t)(w - 1) * DD * DD;
        ushort* WT = WTall + (size_t)w * DD * DD;
        for (int i = t; i < DD * DD; i += 256) {
            int k = i >> 7, nn = i & 127;
            WT[nn * DD + k] = f2b(W[i]);
        }
    } else {
        for (int i = t; i < 3 * 2 * DD; i += 256) stats[i] = 0.f;
    }
}

// ---------------- fused MFMA GEMM ----------------
__global__ __launch_bounds__(256) void gemm_fused(
    const void* __restrict__ Xv, int xf32,
    const ushort* __restrict__ WT,
    const float* __restrict__ bias, const float* __restrict__ scale,
    const float* __restrict__ stats, const float* __restrict__ bng, const float* __restrict__ bnb, float invN,
    const float* __restrict__ uvec, float* __restrict__ logits, int dot_init_mode,
    ushort* __restrict__ Y, int nrows)
{
    __shared__ float As[DD], Bs[DD], Us[DD];
    __shared__ ushort Ys[4][32][YSP];
    int t = threadIdx.x;
    bool has_bn = (stats != nullptr);
    bool has_u  = (uvec != nullptr);
    if (has_bn && t < DD) {
        float mean = stats[t] * invN;
        float var = stats[DD + t] * invN - mean * mean;
        float a = bng[t] * rsqrtf(var + EPS);
        As[t] = a; Bs[t] = bnb[t] - mean * a;
    }
    if (has_u && t < DD) Us[t] = uvec[t];
    if (has_bn || has_u) __syncthreads();

    int wv = t >> 6;
    int lane = t & 63;
    int l15 = lane & 15;
    int kg = lane >> 4;
    int row0 = blockIdx.x * 128 + wv * 32;

    f32x4 acc[2][8];
    #pragma unroll
    for (int mt = 0; mt < 2; mt++)
        #pragma unroll
        for (int nt = 0; nt < 8; nt++) acc[mt][nt] = (f32x4){0.f, 0.f, 0.f, 0.f};

    int rA0 = min(row0 + l15, nrows - 1);
    int rA1 = min(row0 + 16 + l15, nrows - 1);
    float dot0 = 0.f, dot1 = 0.f;

    #pragma unroll
    for (int ks = 0; ks < 4; ks++) {
        U16B a0, a1;
        int d0 = ks * 32 + kg * 8;
        if (xf32) {
            const float* x0 = (const float*)Xv + (size_t)rA0 * DD + d0;
            const float* x1 = (const float*)Xv + (size_t)rA1 * DD + d0;
            f32x4 p0 = *(const f32x4*)x0;
            f32x4 q0 = *(const f32x4*)(x0 + 4);
            f32x4 p1 = *(const f32x4*)x1;
            f32x4 q1 = *(const f32x4*)(x1 + 4);
            a0.s[0]=f2b(p0.x); a0.s[1]=f2b(p0.y); a0.s[2]=f2b(p0.z); a0.s[3]=f2b(p0.w);
            a0.s[4]=f2b(q0.x); a0.s[5]=f2b(q0.y); a0.s[6]=f2b(q0.z); a0.s[7]=f2b(q0.w);
            a1.s[0]=f2b(p1.x); a1.s[1]=f2b(p1.y); a1.s[2]=f2b(p1.z); a1.s[3]=f2b(p1.w);
            a1.s[4]=f2b(q1.x); a1.s[5]=f2b(q1.y); a1.s[6]=f2b(q1.z); a1.s[7]=f2b(q1.w);
        } else {
            const ushort* X = (const ushort*)Xv;
            a0.u = *(((const u32x4*)(X + (size_t)rA0 * DD)) + ks * 4 + kg);
            a1.u = *(((const u32x4*)(X + (size_t)rA1 * DD)) + ks * 4 + kg);
            if (has_bn || has_u) {
                #pragma unroll
                for (int j = 0; j < 8; j++) {
                    float v0 = b2f(a0.s[j]);
                    float v1 = b2f(a1.s[j]);
                    if (has_bn) {
                        float A = As[d0 + j], B = Bs[d0 + j];
                        v0 = fmaxf(fmaf(A, v0, B), 0.f);
                        v1 = fmaxf(fmaf(A, v1, B), 0.f);
                        a0.s[j] = f2b(v0); a1.s[j] = f2b(v1);
                    }
                    if (has_u) {
                        float uu = Us[d0 + j];
                        dot0 = fmaf(v0, uu, dot0);
                        dot1 = fmaf(v1, uu, dot1);
                    }
                }
            }
        }
        #pragma unroll
        for (int nt = 0; nt < 8; nt++) {
            U16B b;
            b.u = ((const u32x4*)(WT + (size_t)(nt * 16 + l15) * DD))[ks * 4 + kg];
            acc[0][nt] = __builtin_amdgcn_mfma_f32_16x16x32_bf16(a0.b, b.b, acc[0][nt], 0, 0, 0);
            acc[1][nt] = __builtin_amdgcn_mfma_f32_16x16x32_bf16(a1.b, b.b, acc[1][nt], 0, 0, 0);
        }
    }

    if (has_u) {
        dot0 += __shfl_xor(dot0, 16); dot0 += __shfl_xor(dot0, 32);
        dot1 += __shfl_xor(dot1, 16); dot1 += __shfl_xor(dot1, 32);
        if (kg == 0) {
            int r0 = row0 + l15, r1 = row0 + 16 + l15;
            if (r0 < nrows) logits[r0] = dot_init_mode ? dot0 : (logits[r0] + dot0);
            if (r1 < nrows) logits[r1] = dot_init_mode ? dot1 : (logits[r1] + dot1);
        }
    }

    // epilogue: bias+scale, stage in LDS, coalesced 16B stores
    #pragma unroll
    for (int mt = 0; mt < 2; mt++) {
        #pragma unroll
        for (int r = 0; r < 4; r++) {
            int lrow = mt * 16 + kg * 4 + r;
            int grow = row0 + lrow;
            float s = scale ? (grow < nrows ? scale[grow] : 0.f) : 1.f;
            #pragma unroll
            for (int nt = 0; nt < 8; nt++) {
                int col = nt * 16 + l15;
                float v = acc[mt][nt][r];
                if (bias) v += bias[col];
                Ys[wv][lrow][col] = f2b(v * s);
            }
        }
    }
    __syncthreads();
    {
        int rr = lane >> 1;
        int hh = lane & 1;
        int grow = row0 + rr;
        if (grow < nrows) {
            const ushort* src = &Ys[wv][rr][hh * 64];
            ushort* dst = Y + (size_t)grow * DD + hh * 64;
            #pragma unroll
            for (int q = 0; q < 8; q++)
                ((u32x4*)dst)[q] = ((const u32x4*)src)[q];
        }
    }
}

// ---------------- aggregation: one wave per node, 16B/lane, 4 edges per wave-instruction ----------------
__global__ __launch_bounds__(256) void aggregate(const ushort* __restrict__ hl2, const int* __restrict__ ebuf,
                                                 const int* __restrict__ offs, const float* __restrict__ dis,
                                                 ushort* __restrict__ aggb, int n) {
    int w = threadIdx.x >> 6;
    int lane = threadIdx.x & 63;
    int g = lane >> 4;        // edge group 0..3
    int c = lane & 15;        // 16B chunk of row
    int v = blockIdx.x * 4 + w;
    if (v >= n) return;
    const u32x4* base = (const u32x4*)hl2;

    float acc[8];
    #pragma unroll
    for (int q = 0; q < 8; q++) acc[q] = 0.f;

    int e0 = offs[v], e1 = offs[v + 1];
    int cnt = (e1 - e0) + 1;   // + self

    #define ACCM(M) { \
        acc[0] += blo((M).x); acc[1] += bhi((M).x); \
        acc[2] += blo((M).y); acc[3] += bhi((M).y); \
        acc[4] += blo((M).z); acc[5] += bhi((M).z); \
        acc[6] += blo((M).w); acc[7] += bhi((M).w); }

    int jb = 0;
    for (; jb + 16 <= cnt; jb += 16) {
        int j0 = jb + g;
        int s0 = (j0 == 0) ? v : ebuf[e0 + j0 - 1];
        int s1 = ebuf[e0 + jb + g + 3];
        int s2 = ebuf[e0 + jb + g + 7];
        int s3 = ebuf[e0 + jb + g + 11];
        u32x4 m0 = base[(size_t)s0 * 16 + c];
        u32x4 m1 = base[(size_t)s1 * 16 + c];
        u32x4 m2 = base[(size_t)s2 * 16 + c];
        u32x4 m3 = base[(size_t)s3 * 16 + c];
        ACCM(m0); ACCM(m1); ACCM(m2); ACCM(m3);
    }
    for (; jb < cnt; jb += 4) {
        int j = jb + g;
        if (j < cnt) {
            int s = (j == 0) ? v : ebuf[e0 + j - 1];
            u32x4 m = base[(size_t)s * 16 + c];
            ACCM(m);
        }
    }
    #undef ACCM

    #pragma unroll
    for (int q = 0; q < 8; q++) {
        acc[q] += __shfl_xor(acc[q], 16);
        acc[q] += __shfl_xor(acc[q], 32);
    }
    if (g == 0) {
        float dv = dis[v];
        u32x4 o;
        o.x = ((uint)f2b(acc[1] * dv) << 16) | (uint)f2b(acc[0] * dv);
        o.y = ((uint)f2b(acc[3] * dv) << 16) | (uint)f2b(acc[2] * dv);
        o.z = ((uint)f2b(acc[5] * dv) << 16) | (uint)f2b(acc[4] * dv);
        o.w = ((uint)f2b(acc[7] * dv) << 16) | (uint)f2b(acc[6] * dv);
        ((u32x4*)aggb)[(size_t)v * 16 + c] = o;
    }
}

// ---------------- batchnorm stats (bf16 input, fp32 accum) ----------------
__global__ __launch_bounds__(1024) void bn_stats_b(const ushort* __restrict__ aggb, float* stats, int n) {
    int lane = threadIdx.x & 63;
    int rg = threadIdx.x >> 6;  // 0..15
    float sx = 0.f, sy = 0.f, qx = 0.f, qy = 0.f;
    for (int i = blockIdx.x * 16 + rg; i < n; i += gridDim.x * 16) {
        uint m = ((const uint*)aggb)[(size_t)i * 64 + lane];
        float vx = blo(m), vy = bhi(m);
        sx += vx; sy += vy; qx += vx * vx; qy += vy * vy;
    }
    __shared__ float4 red[16][64];
    red[rg][lane] = make_float4(sx, sy, qx, qy);
    __syncthreads();
    if (rg == 0) {
        float4 a = red[0][lane];
        #pragma unroll
        for (int r = 1; r < 16; r++) {
            float4 x2 = red[r][lane];
            a.x += x2.x; a.y += x2.y; a.z += x2.z; a.w += x2.w;
        }
        atomicAdd(&stats[2 * lane], a.x);
        atomicAdd(&stats[2 * lane + 1], a.y);
        atomicAdd(&stats[DD + 2 * lane], a.z);
        atomicAdd(&stats[DD + 2 * lane + 1], a.w);
    }
}

// ---------------- last layer: BN+relu+dot+sigmoid+output ----------------
__global__ __launch_bounds__(256) void bn_dot_fin(const ushort* __restrict__ aggb, const float* __restrict__ stats,
                                                  const float* __restrict__ g, const float* __restrict__ b,
                                                  const float* __restrict__ uvec, const float* __restrict__ logits,
                                                  float* __restrict__ out, int n, float invN) {
    __shared__ float As[DD], Bs[DD], Us[DD];
    int t = threadIdx.x;
    if (t < DD) {
        float mean = stats[t] * invN;
        float var = stats[DD + t] * invN - mean * mean;
        float a = g[t] * rsqrtf(var + EPS);
        As[t] = a; Bs[t] = b[t] - mean * a; Us[t] = uvec[t];
    }
    __syncthreads();
    int w = t >> 6, lane = t & 63;
    int v = blockIdx.x * 4 + w;
    if (v >= n) return;
    uint m = ((const uint*)aggb)[(size_t)v * 64 + lane];
    int d0 = 2 * lane;
    float f0 = fmaxf(fmaf(As[d0], blo(m), Bs[d0]), 0.f);
    float f1 = fmaxf(fmaf(As[d0 + 1], bhi(m), Bs[d0 + 1]), 0.f);
    float c = f0 * Us[d0] + f1 * Us[d0 + 1];
    #pragma unroll
    for (int off = 32; off; off >>= 1) c += __shfl_down(c, off);
    if (lane == 0) {
        float xf = logits[v] + c;
        out[v] = xf;
        out[n + v] = 1.f / (1.f + expf(-xf));
    }
}

// ---------------- host ----------------

static inline size_t align_up(size_t x, size_t a) { return (x + a - 1) & ~(a - 1); }

extern "C" void kernel_launch(void* const* d_in, const int* in_sizes, int n_in,
                              void* d_out, int out_size, void* d_ws, size_t ws_size,
                              hipStream_t stream) {
    const float* x       = (const float*)d_in[0];
    const int*   ei      = (const int*)d_in[1];
    const float* emb_w   = (const float*)d_in[2];
    const float* emb_b   = (const float*)d_in[3];
    const float* gcn_w   = (const float*)d_in[4];
    // d_in[5] = gcn_b: no-op (constant shift immediately normalized away by BatchNorm)
    const float* bn_g    = (const float*)d_in[6];
    const float* bn_b    = (const float*)d_in[7];
    const float* skip_w  = (const float*)d_in[8];
    const float* readout = (const float*)d_in[9];
    float* out = (float*)d_out;

    const int N = in_sizes[0] / DD;
    const int E = in_sizes[1] / 2;
    const int NBUK = (N + BUKN - 1) / BUKN;   // 391 <= MAXBUK
    const float invN = 1.0f / N;

    char* p = (char*)d_ws;
    size_t off = 0;
    auto alloc = [&](size_t bytes) { void* r = p + off; off = align_up(off + bytes, 256); return r; };
    float*  dis     = (float*) alloc((size_t)N * 4);
    int*    offs    = (int*)   alloc((size_t)(N + 1) * 4);
    int*    ebuf    = (int*)   alloc((size_t)E * 4);
    uint*   pairs   = (uint*)  alloc((size_t)E * 4);
    int*    gh      = (int*)   alloc((size_t)GCH * NBUK * 4);
    int*    total   = (int*)   alloc((size_t)NBUK * 4);
    int*    bukbase = (int*)   alloc((size_t)(NBUK + 1) * 4);
    float*  u       = (float*) alloc(4 * DD * 4);
    float*  stats   = (float*) alloc(3 * 2 * DD * 4);
    ushort* WTall   = (ushort*)alloc(4 * (size_t)DD * DD * 2);
    float*  logits  = (float*) alloc((size_t)N * 4);
    ushort* hB      = (ushort*)alloc((size_t)N * DD * 2);
    ushort* hl2B    = (ushort*)alloc((size_t)N * DD * 2);
    ushort* aggB    = (ushort*)alloc((size_t)N * DD * 2);
    (void)ws_size;

    int gG = (N + 127) / 128;

    // CSR build (contention-free counting sort, 256-node buckets)
    count_hist<<<GCH, 256, 0, stream>>>(ei, gh, E, NBUK);
    colscan<<<(NBUK + 3) / 4, 256, 0, stream>>>(gh, total, NBUK);
    bukscan<<<1, 1024, 0, stream>>>(total, bukbase, offs, NBUK, N, E);
    scatter<<<GCH, 256, 0, stream>>>(ei, gh, bukbase, pairs, E, NBUK);
    csr_finalize<<<NBUK, 256, 0, stream>>>(pairs, bukbase, offs, dis, ebuf, N);

    prep_small<<<9, 256, 0, stream>>>(skip_w, readout, emb_w, gcn_w, u, WTall, stats);

    // embedding: h = x @ emb_w + emb_b  (reads fp32 x directly)
    gemm_fused<<<gG, 256, 0, stream>>>(x, 1, WTall, emb_b, nullptr,
                                       nullptr, nullptr, nullptr, invN,
                                       nullptr, nullptr, 0, hB, N);

    for (int l = 0; l < 3; l++) {  // layer 3's output is dead (skip uses feats[0..3])
        const ushort* Xin = (l == 0) ? hB : aggB;
        const float* st   = (l == 0) ? nullptr : stats + (size_t)(l - 1) * 2 * DD;
        const float* g    = (l == 0) ? nullptr : bn_g + (size_t)(l - 1) * DD;
        const float* bb   = (l == 0) ? nullptr : bn_b + (size_t)(l - 1) * DD;
        gemm_fused<<<gG, 256, 0, stream>>>(Xin, 0, WTall + (size_t)(l + 1) * DD * DD, nullptr, dis,
                                           st, g, bb, invN,
                                           u + (size_t)l * DD, logits, (l == 0) ? 1 : 0, hl2B, N);
        aggregate<<<(N + 3) / 4, 256, 0, stream>>>(hl2B, ebuf, offs, dis, aggB, N);
        bn_stats_b<<<256, 1024, 0, stream>>>(aggB, stats + (size_t)l * 2 * DD, N);
    }
    // feats[3] = BNrelu(agg_2): out = logits + feats[3].u[3]; sigmoid
    bn_dot_fin<<<(N + 3) / 4, 256, 0, stream>>>(aggB, stats + 2 * 2 * DD, bn_g + 2 * DD, bn_b + 2 * DD,
                                                u + 3 * DD, logits, out, N, invN);
}